// Round 7
// baseline (1372.949 us; speedup 1.0000x reference)
//
#include <hip/hip_runtime.h>
#include <cfloat>

#define NTRAIN 40000
#define NTEST  10000
#define DIM    512
#define NCOMP  64
#define KNN    32

// ---------------- stage-A geometry ----------------
#define NSEG   16
#define SEGC   (NTRAIN / NSEG)          // 2500 train cols per segment (2.56 MB < 4 MB XCD L2)
#define BMT    128                       // test rows per WG
#define BNT    128                       // train cols per WG
#define BK     64                        // K per chunk
#define NTILES ((SEGC + BNT - 1) / BNT)  // 20
#define MTILES ((NTEST + BMT - 1) / BMT) // 79
#define LSEL   8                         // per-(row,bucket) register list length
#define DUMP   16                        // per-(row,seg) merged candidates dumped
#define KCAND  48                        // candidates re-ranked exactly per row
#define CPR    (NSEG * DUMP)             // 256 candidates per row pre-cut

typedef __bf16 bf16x8 __attribute__((ext_vector_type(8)));
typedef float  f32x4  __attribute__((ext_vector_type(4)));
typedef unsigned short u16x8 __attribute__((ext_vector_type(8)));

// ---------------- workspace layout (bytes) ----------------
#define OFF_TRAINBF 0ULL                 // 40000*512*2 = 40,960,000
#define OFF_TESTBF  40960000ULL          // 10000*512*2 = 10,240,000
#define OFF_TRS     51200000ULL          // 40000*4
#define OFF_NPTRS   51360000ULL          // 40000*4
#define OFF_NPTESTS 51520000ULL          // 10000*4
#define OFF_CAND    51560448ULL          // 10000*16*16*4 = 10,240,000
#define OFF_CUT     61800448ULL          // 10000*48*4 = 1,920,000
#define OFF_D2      63720448ULL          // 10000*48*4 = 1,920,000
#define WS_NEED     65640448ULL

// ---------------------------------------------------------------------------
// np-f32 emulation of the harness reference (verified passing rounds 3-6):
//   norms = numpy pairwise sum (128-blocks, 8 accumulators)
//   dot   = sequential f32 FMA chain (BLAS microkernel accumulation order)
//   d2    = f32( f32(ts + trs) - 2*dot ), no FMA contraction
// ---------------------------------------------------------------------------
__device__ __forceinline__ float np_block128_sq(const float* __restrict__ q) {
#pragma clang fp contract(off)
    float r0 = q[0]*q[0], r1 = q[1]*q[1], r2 = q[2]*q[2], r3 = q[3]*q[3];
    float r4 = q[4]*q[4], r5 = q[5]*q[5], r6 = q[6]*q[6], r7 = q[7]*q[7];
    #pragma unroll
    for (int i = 8; i < 128; i += 8) {
        r0 += q[i+0]*q[i+0];
        r1 += q[i+1]*q[i+1];
        r2 += q[i+2]*q[i+2];
        r3 += q[i+3]*q[i+3];
        r4 += q[i+4]*q[i+4];
        r5 += q[i+5]*q[i+5];
        r6 += q[i+6]*q[i+6];
        r7 += q[i+7]*q[i+7];
    }
    return ((r0 + r1) + (r2 + r3)) + ((r4 + r5) + (r6 + r7));
}

__device__ __forceinline__ float np_sq512(const float* __restrict__ q) {
#pragma clang fp contract(off)
    const float b0 = np_block128_sq(q);
    const float b1 = np_block128_sq(q + 128);
    const float b2 = np_block128_sq(q + 256);
    const float b3 = np_block128_sq(q + 384);
    return (b0 + b1) + (b2 + b3);
}

__device__ __forceinline__ float np_dot512(const float* __restrict__ t,
                                           const float* __restrict__ x) {
    float acc = 0.f;
    for (int k = 0; k < DIM; k += 4) {
        const float4 tv = *(const float4*)(t + k);
        const float4 xv = *(const float4*)(x + k);
        acc = fmaf(tv.x, xv.x, acc);
        acc = fmaf(tv.y, xv.y, acc);
        acc = fmaf(tv.z, xv.z, acc);
        acc = fmaf(tv.w, xv.w, acc);
    }
    return acc;
}

__device__ __forceinline__ unsigned short f32_to_bf16_rne(float f) {
    unsigned int u = __float_as_uint(f);
    u += 0x7fffu + ((u >> 16) & 1u);
    return (unsigned short)(u >> 16);
}

__device__ __forceinline__ void global_load_lds16(const void* g, void* l) {
    __builtin_amdgcn_global_load_lds(
        (const __attribute__((address_space(1))) void*)g,
        (__attribute__((address_space(3))) void*)l, 16, 0, 0);
}

// sorted ascending 8-list insert (u32 keys)
__device__ __forceinline__ void kinsert(unsigned key, unsigned (&l)[LSEL]) {
    if (key < l[LSEL - 1]) {
        #pragma unroll
        for (int p = LSEL - 1; p >= 1; --p) {
            const bool up = key < l[p - 1];
            const unsigned nv = up ? l[p - 1] : key;
            if (key < l[p]) l[p] = nv;
        }
        if (key < l[0]) l[0] = key;
    }
}

// ======================= K0a: f32 -> bf16 + approx train norms =======================
__global__ void prep_convert(const float* __restrict__ train_x,
                             const float* __restrict__ test_x,
                             unsigned short* __restrict__ train_bf,
                             unsigned short* __restrict__ test_bf,
                             float* __restrict__ trs)
{
    const int wid = threadIdx.x >> 6, lane = threadIdx.x & 63;
    const int row = blockIdx.x * 4 + wid;              // 0..49999
    if (row >= NTRAIN + NTEST) return;
    const bool is_train = row < NTRAIN;
    const float* src = is_train ? (train_x + (size_t)row * DIM)
                                : (test_x + (size_t)(row - NTRAIN) * DIM);
    unsigned short* dst = is_train ? (train_bf + (size_t)row * DIM)
                                   : (test_bf + (size_t)(row - NTRAIN) * DIM);
    const float4 v0 = *(const float4*)(src + lane * 8);
    const float4 v1 = *(const float4*)(src + lane * 8 + 4);
    const float f[8] = {v0.x, v0.y, v0.z, v0.w, v1.x, v1.y, v1.z, v1.w};
    u16x8 o;
    float ss = 0.f;
    #pragma unroll
    for (int j = 0; j < 8; ++j) {
        o[j] = f32_to_bf16_rne(f[j]);
        ss += f[j] * f[j];
    }
    *(u16x8*)(dst + lane * 8) = o;
    if (is_train) {
        #pragma unroll
        for (int d = 1; d < 64; d <<= 1) ss += __shfl_xor(ss, d);
        if (lane == 0) trs[row] = ss;
    }
}

// ======================= K0b: exact np norms =======================
__global__ void prep_npnorm(const float* __restrict__ train_x,
                            const float* __restrict__ test_x,
                            float* __restrict__ np_trs,
                            float* __restrict__ np_tests)
{
    const int t = blockIdx.x * 256 + threadIdx.x;
    if (t < NTRAIN)                np_trs[t] = np_sq512(train_x + (size_t)t * DIM);
    else if (t < NTRAIN + NTEST)   np_tests[t - NTRAIN] = np_sq512(test_x + (size_t)(t - NTRAIN) * DIM);
}

// ======================= K1: MFMA candidate generation =======================
// WG: 128 test rows x 128 train cols. 4 waves (2x2), each 64 train x 64 test,
// acc[4][4] (64 VGPR). BK=64 chunks, round-5-proven barrier structure:
//   sync; issue 8 global_load_lds; sync(drain); ds_read + 32 MFMA.
// NSEG=16 -> 2.56 MB segment fits XCD L2 (kills the HBM-miss drains that
// round 5/6 paid). Two-phase grid keeps ONE seg per XCD at a time.
// mfma(A=train, B=test): lane holds test row 16j+l15, train col i*16+l4*4+r
// (mapping verified rounds 4-6). Register top-8 lists per j, float-gated.
__global__ __launch_bounds__(256, 3)
void stageA(const unsigned short* __restrict__ train_bf,
            const unsigned short* __restrict__ test_bf,
            const float* __restrict__ trs,
            unsigned* __restrict__ cand)
{
    __shared__ unsigned short AB[2048 * 8];   // 32 KB: test granules 0..1023, train 1024..2047
    __shared__ float colTrs[BNT];             // 512 B

    const int tid  = threadIdx.x;
    const int wid  = tid >> 6;
    const int lane = tid & 63;
    const int l15 = lane & 15, l4 = lane >> 4;
    const int wr = wid >> 1, wc = wid & 1;

    const int bid  = blockIdx.x;
    const int half = (bid >= MTILES * 8) ? 1 : 0;
    const int b2   = bid - half * (MTILES * 8);
    const int seg  = (b2 & 7) + half * 8;      // XCD-pinned: b2&7 == XCD
    const int m_base = (b2 >> 3) * BMT;
    const int seg0 = seg * SEGC;

    // --- fixed per-thread staging assignments (hoisted address math) ---
    // loads l=0..3: test granules d=l*256+tid -> LDS granule d
    // loads l=0..3: train granules          -> LDS granule 1024+d
    int tOffE[4], trRow[4], trG[4];
    #pragma unroll
    for (int l = 0; l < 4; ++l) {
        const int d = l * 256 + tid;
        const int r = d >> 3;
        const int g = (d & 7) ^ (r & 7);       // inverse swizzle on SOURCE (LDS linear)
        int gr = m_base + r; if (gr > NTEST - 1) gr = NTEST - 1;
        tOffE[l] = gr * DIM + g * 8;           // element offset into test_bf
        trRow[l] = r;
        trG[l]   = g;
    }

    // --- fixed fragment LDS byte offsets (h=0; h=1 is ^64) ---
    int aOff[4], bOff[4];
    #pragma unroll
    for (int i = 0; i < 4; ++i) {
        const int arow = wc * 64 + i * 16 + l15;   // train col within tile
        aOff[i] = (1024 + arow * 8 + (l4 ^ (arow & 7))) * 16;
        const int brow = wr * 64 + i * 16 + l15;   // test row within tile
        bOff[i] = (brow * 8 + (l4 ^ (brow & 7))) * 16;
    }

    unsigned lst[4][LSEL];
    float tailF[4];
    #pragma unroll
    for (int j = 0; j < 4; ++j) {
        tailF[j] = __uint_as_float(0x7FFFFFFFu);   // NaN: !(s>=NaN) admits all
        #pragma unroll
        for (int s = 0; s < LSEL; ++s) lst[j][s] = 0xFFFFFFFFu;
    }

    f32x4 acc[4][4];
    #pragma unroll
    for (int i = 0; i < 4; ++i)
        #pragma unroll
        for (int j = 0; j < 4; ++j) acc[i][j] = (f32x4){0.f, 0.f, 0.f, 0.f};

    const unsigned short* trainSeg = train_bf + (size_t)seg0 * DIM;

    for (int tile = 0; tile < NTILES; ++tile) {
        const int n_base = tile * BNT;
        int trOffE[4];
        #pragma unroll
        for (int l = 0; l < 4; ++l) {
            int sr = n_base + trRow[l]; if (sr > SEGC - 1) sr = SEGC - 1;
            trOffE[l] = sr * DIM + trG[l] * 8;
        }

        for (int kc = 0; kc < DIM / BK; ++kc) {
            const int kE = kc * BK;
            __syncthreads();                       // previous LDS consumers done
            #pragma unroll
            for (int l = 0; l < 4; ++l)
                global_load_lds16(test_bf + tOffE[l] + kE, &AB[(l * 256 + tid) * 8]);
            #pragma unroll
            for (int l = 0; l < 4; ++l)
                global_load_lds16(trainSeg + trOffE[l] + kE, &AB[(1024 + l * 256 + tid) * 8]);
            if (kc == 0 && tid < BNT) {
                int c = n_base + tid; if (c > SEGC - 1) c = SEGC - 1;
                colTrs[tid] = trs[seg0 + c];
            }
            __syncthreads();                       // drain + barrier
            #pragma unroll
            for (int h = 0; h < 2; ++h) {          // two K=32 halves
                const int hx = h * 64;             // byte XOR selects k-half granule
                bf16x8 aF[4];
                #pragma unroll
                for (int i = 0; i < 4; ++i)
                    aF[i] = *(const bf16x8*)((const char*)AB + (aOff[i] ^ hx));
                #pragma unroll
                for (int j = 0; j < 4; ++j) {
                    const bf16x8 bF = *(const bf16x8*)((const char*)AB + (bOff[j] ^ hx));
                    #pragma unroll
                    for (int i = 0; i < 4; ++i)
                        acc[i][j] = __builtin_amdgcn_mfma_f32_16x16x32_bf16(
                            aF[i], bF, acc[i][j], 0, 0, 0);
                }
            }
        }

        // ---- end of tile: float-gated in-register selection (no barriers) ----
        #pragma unroll
        for (int i = 0; i < 4; ++i) {
            float ctr[4];
            #pragma unroll
            for (int r = 0; r < 4; ++r)
                ctr[r] = colTrs[wc * 64 + i * 16 + l4 * 4 + r];
            #pragma unroll
            for (int j = 0; j < 4; ++j) {
                #pragma unroll
                for (int r = 0; r < 4; ++r) {
                    const int lidx = n_base + wc * 64 + i * 16 + l4 * 4 + r;
                    const float s = fmaf(-2.f, acc[i][j][r], ctr[r]);
                    if (lidx < SEGC && !(s >= tailF[j])) {
                        const unsigned u    = __float_as_uint(s);
                        const unsigned mono = u ^ ((unsigned)((int)u >> 31) | 0x80000000u);
                        const unsigned key  = (mono & 0xFFFFF000u) | (unsigned)lidx;
                        kinsert(key, lst[j]);
                        const unsigned tk = lst[j][LSEL - 1] | 0xFFFu;   // tail rounded up
                        const unsigned tu = (tk & 0x80000000u) ? (tk ^ 0x80000000u) : ~tk;
                        tailF[j] = __uint_as_float(tu);
                    }
                }
                acc[i][j] = (f32x4){0.f, 0.f, 0.f, 0.f};
            }
        }
    }

    // -------- end-of-WG merge (overlaid on AB): per row, 8 buckets x 8 -> top-16 --------
    unsigned* MgU = (unsigned*)AB;                 // [32 rows][8 buckets][LSEL]
    #pragma unroll
    for (int c = 0; c < 4; ++c) {                  // chunk c = rows [c*32, c*32+32)
        __syncthreads();                           // (first iter: last compute done)
        if (wr == (c >> 1)) {
            #pragma unroll
            for (int jj = 0; jj < 2; ++jj) {
                const int j = (c & 1) * 2 + jj;
                #pragma unroll
                for (int s = 0; s < LSEL; ++s)
                    MgU[((jj * 16 + l15) * 8 + (wc * 4 + l4)) * 8 + s] = lst[j][s];
            }
        }
        __syncthreads();
        const int mrow = tid >> 3, mb = tid & 7;
        unsigned mine[LSEL];
        #pragma unroll
        for (int s = 0; s < LSEL; ++s) mine[s] = MgU[(mrow * 8 + mb) * 8 + s];
        int rank[LSEL];
        #pragma unroll
        for (int s = 0; s < LSEL; ++s) rank[s] = 0;
        #pragma unroll
        for (int ob = 0; ob < 8; ++ob) {
            #pragma unroll
            for (int os = 0; os < LSEL; ++os) {
                const unsigned ok = MgU[(mrow * 8 + ob) * 8 + os];
                #pragma unroll
                for (int s = 0; s < LSEL; ++s) rank[s] += (ok < mine[s]) ? 1 : 0;
            }
        }
        const int grow = m_base + c * 32 + mrow;
        if (grow < NTEST) {
            #pragma unroll
            for (int s = 0; s < LSEL; ++s)
                if (rank[s] < DUMP)
                    cand[((size_t)grow * NSEG + seg) * DUMP + rank[s]] = mine[s];
        }
    }
}

// ======================= K2: cut 256 -> 48 by approx key =======================
__global__ void cut48k(const unsigned* __restrict__ cand, int* __restrict__ cut)
{
    __shared__ unsigned long long C[4][CPR];           // 4 x 256 x 8B = 8 KB
    const int wid = threadIdx.x >> 6, lane = threadIdx.x & 63;
    const int row = blockIdx.x * 4 + wid;              // grid*4 == NTEST exactly
    #pragma unroll
    for (int t = 0; t < 4; ++t) {
        const int e = lane + t * 64;
        const unsigned key = cand[(size_t)row * CPR + e];
        const int sg = e >> 4;                         // DUMP = 16
        const unsigned gidx = (unsigned)(sg * SEGC) + (key & 0xFFFu);
        C[wid][e] = ((unsigned long long)(key >> 12) << 32) | gidx;
    }
    __syncthreads();
    #pragma unroll
    for (int t = 0; t < 4; ++t) {
        const int e = lane + t * 64;
        const unsigned long long mk = C[wid][e];
        int rank = 0;
        for (int o = 0; o < CPR; ++o) rank += (C[wid][o] < mk) ? 1 : 0;
        if (rank < KCAND) cut[(size_t)row * KCAND + rank] = (int)(mk & 0xFFFFFFFFULL);
    }
}

// ======================= K3: exact np-f32 d2 for 48 candidates =======================
__global__ void npd2_kernel(const float* __restrict__ train_x,
                            const float* __restrict__ test_x,
                            const float* __restrict__ np_trs,
                            const float* __restrict__ np_tests,
                            const int* __restrict__ cut,
                            float* __restrict__ d2)
{
#pragma clang fp contract(off)
    const int T = blockIdx.x * 256 + threadIdx.x;
    if (T >= NTEST * KCAND) return;
    const int row = T / KCAND;
    const int idx = cut[T];
    const float dt = np_dot512(test_x + (size_t)row * DIM, train_x + (size_t)idx * DIM);
    const float Tv = np_tests[row] + np_trs[idx];   // f32 round
    const float w  = 2.0f * dt;                     // exact
    d2[T] = Tv - w;                                 // f32 round, no contraction
}

// ======================= K4: top-32 select + label mean =======================
__global__ void select_out(const float* __restrict__ train_y,
                           const int* __restrict__ cut,
                           const float* __restrict__ d2,
                           float* __restrict__ out)
{
    __shared__ float D[4][KCAND];
    __shared__ int   I[4][KCAND];
    __shared__ int   S[4][KNN];
    const int wid = threadIdx.x >> 6, lane = threadIdx.x & 63;
    const int row = blockIdx.x * 4 + wid;        // grid*4 == NTEST exactly
    if (lane < KCAND) {
        D[wid][lane] = d2[(size_t)row * KCAND + lane];
        I[wid][lane] = cut[(size_t)row * KCAND + lane];
    }
    __syncthreads();
    if (lane < KCAND) {
        const float ms = D[wid][lane]; const int mi = I[wid][lane];
        int rank = 0;
        #pragma unroll
        for (int o = 0; o < KCAND; ++o)
            rank += (D[wid][o] < ms || (D[wid][o] == ms && I[wid][o] < mi)) ? 1 : 0;
        if (rank < KNN) S[wid][rank] = mi;       // (dist, idx) order == lax.top_k
    }
    __syncthreads();
    float s = 0.f;
    #pragma unroll
    for (int n = 0; n < KNN; ++n)
        s += train_y[(size_t)S[wid][n] * NCOMP + lane];
    out[(size_t)row * NCOMP + lane] = s * (1.0f / KNN);
}

// ======================= fallback: round-3 monolithic kernel =======================
#define FM_TILE 32
#define FN_TILE 256
#define FK_CHUNK 16
__global__ __launch_bounds__(256, 2)
void knn_fallback(const float* __restrict__ train_x,
                  const float* __restrict__ train_y,
                  const float* __restrict__ test_x,
                  float* __restrict__ out)
{
    __shared__ float As[FK_CHUNK][FM_TILE];
    __shared__ float Bs[FK_CHUNK][FN_TILE];
    __shared__ float Scb[FM_TILE][FN_TILE + 1];
    __shared__ float colSq[FN_TILE];
    __shared__ float topD[FM_TILE][64];
    __shared__ int   topI[FM_TILE][64];

    const int tid    = threadIdx.x;
    const int m_base = blockIdx.x * FM_TILE;
    const int tx     = tid & 31;
    const int ty     = tid >> 5;

    for (int i = tid; i < FM_TILE * 64; i += 256) {
        (&topD[0][0])[i] = FLT_MAX;
        (&topI[0][0])[i] = 0;
    }
    float rowMax = FLT_MAX;
    const int a_row  = tid >> 2;
    const int a_k    = (tid & 3) * 4;
    const int a_grow = (m_base + a_row < NTEST) ? (m_base + a_row) : (NTEST - 1);

    for (int n_base = 0; n_base < NTRAIN; n_base += FN_TILE) {
        float accf[4][8];
        #pragma unroll
        for (int i = 0; i < 4; ++i)
            #pragma unroll
            for (int j = 0; j < 8; ++j) accf[i][j] = 0.f;
        int b_row = n_base + tid;
        if (b_row >= NTRAIN) b_row = NTRAIN - 1;
        const float* bp = train_x + (size_t)b_row * DIM;
        float sq_acc = 0.f;
        for (int k_base = 0; k_base < DIM; k_base += FK_CHUNK) {
            __syncthreads();
            if (tid < 128) {
                const float4 v = *(const float4*)(test_x + (size_t)a_grow * DIM + k_base + a_k);
                As[a_k + 0][a_row] = v.x; As[a_k + 1][a_row] = v.y;
                As[a_k + 2][a_row] = v.z; As[a_k + 3][a_row] = v.w;
            }
            {
                const float4* tp = (const float4*)(bp + k_base);
                const float4 v0 = tp[0], v1 = tp[1], v2 = tp[2], v3 = tp[3];
                Bs[0][tid]=v0.x; Bs[1][tid]=v0.y; Bs[2][tid]=v0.z; Bs[3][tid]=v0.w;
                Bs[4][tid]=v1.x; Bs[5][tid]=v1.y; Bs[6][tid]=v1.z; Bs[7][tid]=v1.w;
                Bs[8][tid]=v2.x; Bs[9][tid]=v2.y; Bs[10][tid]=v2.z; Bs[11][tid]=v2.w;
                Bs[12][tid]=v3.x; Bs[13][tid]=v3.y; Bs[14][tid]=v3.z; Bs[15][tid]=v3.w;
                sq_acc += v0.x*v0.x+v0.y*v0.y+v0.z*v0.z+v0.w*v0.w
                        + v1.x*v1.x+v1.y*v1.y+v1.z*v1.z+v1.w*v1.w
                        + v2.x*v2.x+v2.y*v2.y+v2.z*v2.z+v2.w*v2.w
                        + v3.x*v3.x+v3.y*v3.y+v3.z*v3.z+v3.w*v3.w;
            }
            __syncthreads();
            #pragma unroll
            for (int k = 0; k < FK_CHUNK; ++k) {
                const float4 av  = *(const float4*)&As[k][ty * 4];
                const float4 bv0 = *(const float4*)&Bs[k][tx * 8];
                const float4 bv1 = *(const float4*)&Bs[k][tx * 8 + 4];
                const float a[4] = {av.x, av.y, av.z, av.w};
                const float b[8] = {bv0.x, bv0.y, bv0.z, bv0.w, bv1.x, bv1.y, bv1.z, bv1.w};
                #pragma unroll
                for (int i = 0; i < 4; ++i)
                    #pragma unroll
                    for (int j = 0; j < 8; ++j)
                        accf[i][j] = fmaf(a[i], b[j], accf[i][j]);
            }
        }
        colSq[tid] = sq_acc;
        __syncthreads();
        #pragma unroll
        for (int i = 0; i < 4; ++i)
            #pragma unroll
            for (int j = 0; j < 8; ++j) {
                const int c = tx * 8 + j;
                const int gcol = n_base + c;
                Scb[ty * 4 + i][c] = (gcol < NTRAIN) ? (colSq[c] - 2.f * accf[i][j]) : FLT_MAX;
            }
        __syncthreads();
        if (tid < FM_TILE) {
            float rmax = rowMax;
            for (int c = 0; c < FN_TILE; ++c) {
                const float s = Scb[tid][c];
                if (s < rmax) {
                    int bi = 0; float bv = topD[tid][0]; int bidx = topI[tid][0];
                    #pragma unroll
                    for (int i = 1; i < 64; ++i) {
                        const float v = topD[tid][i]; const int idv = topI[tid][i];
                        if (v > bv || (v == bv && idv > bidx)) { bv = v; bi = i; bidx = idv; }
                    }
                    topD[tid][bi] = s; topI[tid][bi] = n_base + c;
                    float nm = -FLT_MAX;
                    #pragma unroll
                    for (int i = 0; i < 64; ++i) nm = fmaxf(nm, topD[tid][i]);
                    rmax = nm;
                }
            }
            rowMax = rmax;
        }
        __syncthreads();
    }
    float* Sf = &Scb[0][0];
    {
#pragma clang fp contract(off)
        const int r = tid >> 3, j0 = tid & 7;
        int grow = m_base + r; if (grow >= NTEST) grow = NTEST - 1;
        const float* tp = test_x + (size_t)grow * DIM;
        const float ts = np_sq512(tp);
        for (int jj = j0; jj < 64; jj += 8) {
            const int idx = topI[r][jj];
            const float* xp = train_x + (size_t)idx * DIM;
            const float trsv = np_sq512(xp);
            const float dt = np_dot512(tp, xp);
            const float T = ts + trsv;
            const float w = 2.0f * dt;
            Sf[r * 64 + jj] = T - w;
        }
    }
    __syncthreads();
    int* sel = (int*)&topD[0][0];
    if (tid < FM_TILE) {
        const int r = tid;
        unsigned long long used = 0ULL;
        for (int p = 0; p < KNN; ++p) {
            float bv = FLT_MAX; int bj = 0; int bidx = 0x7fffffff;
            for (int j = 0; j < 64; ++j) {
                if (used & (1ULL << j)) continue;
                const float v = Sf[r * 64 + j];
                const int idv = topI[r][j];
                if (v < bv || (v == bv && idv < bidx)) { bv = v; bj = j; bidx = idv; }
            }
            used |= (1ULL << bj);
            sel[r * KNN + p] = bidx;
        }
    }
    __syncthreads();
    const int r = tid >> 3, c0 = (tid & 7) * 8;
    const int grow = m_base + r;
    if (grow < NTEST) {
        float s0=0,s1=0,s2=0,s3=0,s4=0,s5=0,s6=0,s7=0;
        for (int n = 0; n < KNN; ++n) {
            const float* yp = train_y + (size_t)sel[r * KNN + n] * NCOMP + c0;
            const float4 y0 = *(const float4*)yp;
            const float4 y1 = *(const float4*)(yp + 4);
            s0+=y0.x; s1+=y0.y; s2+=y0.z; s3+=y0.w;
            s4+=y1.x; s5+=y1.y; s6+=y1.z; s7+=y1.w;
        }
        const float inv = 1.0f / KNN;
        float* op = out + (size_t)grow * NCOMP + c0;
        *(float4*)op       = make_float4(s0*inv, s1*inv, s2*inv, s3*inv);
        *(float4*)(op + 4) = make_float4(s4*inv, s5*inv, s6*inv, s7*inv);
    }
}

// ======================= launcher =======================
extern "C" void kernel_launch(void* const* d_in, const int* in_sizes, int n_in,
                              void* d_out, int out_size, void* d_ws, size_t ws_size,
                              hipStream_t stream) {
    const float* train_x = (const float*)d_in[0];
    const float* train_y = (const float*)d_in[1];
    const float* test_x  = (const float*)d_in[2];
    float* out = (float*)d_out;

    if (ws_size < WS_NEED) {
        knn_fallback<<<(NTEST + FM_TILE - 1) / FM_TILE, 256, 0, stream>>>(
            train_x, train_y, test_x, out);
        return;
    }

    char* ws = (char*)d_ws;
    unsigned short* train_bf = (unsigned short*)(ws + OFF_TRAINBF);
    unsigned short* test_bf  = (unsigned short*)(ws + OFF_TESTBF);
    float*  trs      = (float*)(ws + OFF_TRS);
    float*  np_trs   = (float*)(ws + OFF_NPTRS);
    float*  np_tests = (float*)(ws + OFF_NPTESTS);
    unsigned* cand   = (unsigned*)(ws + OFF_CAND);
    int*    cut      = (int*)(ws + OFF_CUT);
    float*  d2       = (float*)(ws + OFF_D2);

    prep_convert<<<(NTRAIN + NTEST) / 4, 256, 0, stream>>>(train_x, test_x, train_bf, test_bf, trs);
    prep_npnorm<<<(NTRAIN + NTEST + 255) / 256, 256, 0, stream>>>(train_x, test_x, np_trs, np_tests);
    stageA<<<MTILES * NSEG, 256, 0, stream>>>(train_bf, test_bf, trs, cand);
    cut48k<<<NTEST / 4, 256, 0, stream>>>(cand, cut);
    npd2_kernel<<<(NTEST * KCAND + 255) / 256, 256, 0, stream>>>(train_x, test_x, np_trs, np_tests, cut, d2);
    select_out<<<NTEST / 4, 256, 0, stream>>>(train_y, cut, d2, out);
}

// Round 10
// 1116.565 us; speedup vs baseline: 1.2296x; 1.2296x over previous
//
#include <hip/hip_runtime.h>
#include <cfloat>

#define NTRAIN 40000
#define NTEST  10000
#define DIM    512
#define DIMP   544                       // 512 data + 2 norm components + 30 zeros
#define NCOMP  64
#define KNN    32

// ---------------- stage-A geometry ----------------
#define NSEG   8
#define SEGC   (NTRAIN / NSEG)          // 5000
#define BMT    128                       // test rows per WG
#define BNT    128                       // train cols per WG
#define BK2    32                        // K per pipeline step
#define KSTEPS (DIMP / BK2)              // 17
#define NTILES ((SEGC + BNT - 1) / BNT)  // 40
#define NSTEPS (NTILES * KSTEPS)         // 680
#define MTILES ((NTEST + BMT - 1) / BMT) // 79
#define LSEL   8
#define DUMP   24                        // per-(row,seg) candidates dumped
#define KCAND  48
#define CPR    (NSEG * DUMP)             // 192

typedef __bf16 bf16x8 __attribute__((ext_vector_type(8)));
typedef float  f32x4  __attribute__((ext_vector_type(4)));
typedef unsigned short u16x8 __attribute__((ext_vector_type(8)));

// ---------------- workspace layout (bytes) ----------------
#define OFF_TRAINBF 0ULL                 // 40000*544*2 = 43,520,000
#define OFF_TESTBF  43520000ULL          // 10000*544*2 = 10,880,000
#define OFF_NPTRS   54400000ULL          // 40000*4
#define OFF_NPTESTS 54560000ULL          // 10000*4
#define OFF_CAND    54600000ULL          // 10000*8*24*4 = 7,680,000
#define OFF_CUT     62280000ULL          // 10000*48*4
#define OFF_D2      64200000ULL          // 10000*48*4
#define WS_NEED     66120000ULL

// Compile-time memory fence (no instructions). Raw s_barrier is IntrNoMem at
// IR level, so memory ops (including global_load_lds!) may legally cross it.
// EVERY raw s_barrier must be sandwiched: MEMFENCE -> s_barrier -> MEMFENCE.
// Round-9 failure: the fence AFTER barrier-2 was missing, letting the STAGE
// LDS-DMA hoist above the barrier and overwrite AB[cur] mid-read.
#define MEMFENCE() asm volatile("" ::: "memory")

// ---------------------------------------------------------------------------
// np-f32 emulation of the harness reference (verified rounds 3-7)
// ---------------------------------------------------------------------------
__device__ __forceinline__ float np_block128_sq(const float* __restrict__ q) {
#pragma clang fp contract(off)
    float r0 = q[0]*q[0], r1 = q[1]*q[1], r2 = q[2]*q[2], r3 = q[3]*q[3];
    float r4 = q[4]*q[4], r5 = q[5]*q[5], r6 = q[6]*q[6], r7 = q[7]*q[7];
    #pragma unroll
    for (int i = 8; i < 128; i += 8) {
        r0 += q[i+0]*q[i+0];
        r1 += q[i+1]*q[i+1];
        r2 += q[i+2]*q[i+2];
        r3 += q[i+3]*q[i+3];
        r4 += q[i+4]*q[i+4];
        r5 += q[i+5]*q[i+5];
        r6 += q[i+6]*q[i+6];
        r7 += q[i+7]*q[i+7];
    }
    return ((r0 + r1) + (r2 + r3)) + ((r4 + r5) + (r6 + r7));
}

__device__ __forceinline__ float np_sq512(const float* __restrict__ q) {
#pragma clang fp contract(off)
    const float b0 = np_block128_sq(q);
    const float b1 = np_block128_sq(q + 128);
    const float b2 = np_block128_sq(q + 256);
    const float b3 = np_block128_sq(q + 384);
    return (b0 + b1) + (b2 + b3);
}

__device__ __forceinline__ float np_dot512(const float* __restrict__ t,
                                           const float* __restrict__ x) {
    float acc = 0.f;
    for (int k = 0; k < DIM; k += 4) {
        const float4 tv = *(const float4*)(t + k);
        const float4 xv = *(const float4*)(x + k);
        acc = fmaf(tv.x, xv.x, acc);
        acc = fmaf(tv.y, xv.y, acc);
        acc = fmaf(tv.z, xv.z, acc);
        acc = fmaf(tv.w, xv.w, acc);
    }
    return acc;
}

__device__ __forceinline__ unsigned short f32_to_bf16_rne(float f) {
    unsigned int u = __float_as_uint(f);
    u += 0x7fffu + ((u >> 16) & 1u);
    return (unsigned short)(u >> 16);
}

__device__ __forceinline__ void global_load_lds16(const void* g, void* l) {
    __builtin_amdgcn_global_load_lds(
        (const __attribute__((address_space(1))) void*)g,
        (__attribute__((address_space(3))) void*)l, 16, 0, 0);
}

// sorted ascending 8-list insert (u32 keys)
__device__ __forceinline__ void kinsert(unsigned key, unsigned (&l)[LSEL]) {
    if (key < l[LSEL - 1]) {
        #pragma unroll
        for (int p = LSEL - 1; p >= 1; --p) {
            const bool up = key < l[p - 1];
            const unsigned nv = up ? l[p - 1] : key;
            if (key < l[p]) l[p] = nv;
        }
        if (key < l[0]) l[0] = key;
    }
}

// ======================= K0a: f32 -> padded bf16 (norms folded into pads) =======================
// train row: [512 data][-trs/2 hi][-trs/2 residual lo][30 zeros]
// test  row: [512 data][1.0][1.0][30 zeros]
// => MFMA acc over DIMP = dot - trs/2 + eps  (|eps| <~ 0.004); score rank == rank of -acc.
__global__ void prep_convert(const float* __restrict__ train_x,
                             const float* __restrict__ test_x,
                             unsigned short* __restrict__ train_bf,
                             unsigned short* __restrict__ test_bf)
{
    const int wid = threadIdx.x >> 6, lane = threadIdx.x & 63;
    const int row = blockIdx.x * 4 + wid;              // 0..49999
    if (row >= NTRAIN + NTEST) return;
    const bool is_train = row < NTRAIN;
    const float* src = is_train ? (train_x + (size_t)row * DIM)
                                : (test_x + (size_t)(row - NTRAIN) * DIM);
    unsigned short* dst = is_train ? (train_bf + (size_t)row * DIMP)
                                   : (test_bf + (size_t)(row - NTRAIN) * DIMP);
    const float4 v0 = *(const float4*)(src + lane * 8);
    const float4 v1 = *(const float4*)(src + lane * 8 + 4);
    const float f[8] = {v0.x, v0.y, v0.z, v0.w, v1.x, v1.y, v1.z, v1.w};
    u16x8 o;
    float ss = 0.f;
    #pragma unroll
    for (int j = 0; j < 8; ++j) {
        o[j] = f32_to_bf16_rne(f[j]);
        ss += f[j] * f[j];
    }
    *(u16x8*)(dst + lane * 8) = o;
    #pragma unroll
    for (int d = 1; d < 64; d <<= 1) ss += __shfl_xor(ss, d);   // all lanes hold sum
    if (lane < 4) {
        u16x8 p = (u16x8){0,0,0,0,0,0,0,0};
        if (lane == 0) {
            if (is_train) {
                const float c0f = -0.5f * ss;
                const unsigned short c0 = f32_to_bf16_rne(c0f);
                const float c1f = c0f - __uint_as_float((unsigned)c0 << 16);
                p[0] = c0; p[1] = f32_to_bf16_rne(c1f);
            } else {
                p[0] = 0x3F80; p[1] = 0x3F80;                   // 1.0, 1.0
            }
        }
        *(u16x8*)(dst + 512 + lane * 8) = p;
    }
}

// ======================= K0b: exact np norms (on original f32 data) =======================
__global__ void prep_npnorm(const float* __restrict__ train_x,
                            const float* __restrict__ test_x,
                            float* __restrict__ np_trs,
                            float* __restrict__ np_tests)
{
    const int t = blockIdx.x * 256 + threadIdx.x;
    if (t < NTRAIN)                np_trs[t] = np_sq512(train_x + (size_t)t * DIM);
    else if (t < NTRAIN + NTEST)   np_tests[t - NTRAIN] = np_sq512(test_x + (size_t)(t - NTRAIN) * DIM);
}

// ======================= K1: MFMA candidate generation (depth-3 counted-vmcnt pipeline) =======================
// 128x128 tile, 4 waves (2x2 of 64x64). K flattened: 40 tiles x 17 steps of BK2=32.
// 3 LDS buffers; per step:
//   vmcnt(8) [own oldest 4 landed] -> FENCE s_barrier FENCE ->
//   8 ds_read_b128 + 16 MFMA -> FENCE s_barrier FENCE -> issue step g+3.
// Both barriers are fully fenced: without the post-barrier fence the STAGE
// LDS-DMA (a memory op; s_barrier is IntrNoMem) can hoist above the barrier
// and overwrite AB[cur] while other waves still read it (rounds 8-9 tripwire).
// No vmcnt(0) in the loop (T3/T4); zero other vmem in the loop (norms folded).
__global__ __launch_bounds__(256, 3)
void stageA(const unsigned short* __restrict__ train_bf,
            const unsigned short* __restrict__ test_bf,
            unsigned* __restrict__ cand)
{
    __shared__ unsigned short AB[3][1024 * 8];   // 3 x 16 KB (test granules 0..511, train 512..1023)

    const int tid  = threadIdx.x;
    const int wid  = tid >> 6;
    const int lane = tid & 63;
    const int l15 = lane & 15, l4 = lane >> 4;
    const int wr = wid >> 1, wc = wid & 1;

    const int seg    = blockIdx.x & 7;
    const int m_base = (blockIdx.x >> 3) * BMT;
    const int seg0   = seg * SEGC;

    // --- per-thread staging sources (element offsets; +k at issue) ---
    int tS[2], trR[2], trG2[2];
    #pragma unroll
    for (int l = 0; l < 2; ++l) {
        const int d = l * 256 + tid;
        const int r = d >> 2;
        const int srcg = (d & 3) ^ ((r >> 1) & 3);   // inverse swizzle on SOURCE (LDS linear)
        int grow = m_base + r; if (grow > NTEST - 1) grow = NTEST - 1;
        tS[l]   = grow * DIMP + srcg * 8;
        trR[l]  = r;
        trG2[l] = srcg;
    }

    // --- fragment LDS element offsets within a buffer ---
    int aOffE[4], bOffE[4];
    #pragma unroll
    for (int i = 0; i < 4; ++i) {
        const int arow = wc * 64 + i * 16 + l15;     // train col
        aOffE[i] = (512 + arow * 4 + (l4 ^ ((arow >> 1) & 3))) * 8;
        const int brow = wr * 64 + i * 16 + l15;     // test row
        bOffE[i] = (brow * 4 + (l4 ^ ((brow >> 1) & 3))) * 8;
    }

    unsigned lst[4][LSEL];
    float tailF[4];
    #pragma unroll
    for (int j = 0; j < 4; ++j) {
        tailF[j] = __uint_as_float(0x7FFFFFFFu);     // NaN: !(f>=NaN) admits all
        #pragma unroll
        for (int s = 0; s < LSEL; ++s) lst[j][s] = 0xFFFFFFFFu;
    }

    f32x4 acc[4][4];
    #pragma unroll
    for (int i = 0; i < 4; ++i)
        #pragma unroll
        for (int j = 0; j < 4; ++j) acc[i][j] = (f32x4){0.f, 0.f, 0.f, 0.f};

    // staging coords (3 steps ahead of compute)
    int trS[2];
    #pragma unroll
    for (int l = 0; l < 2; ++l) {
        int rc = trR[l]; if (rc > SEGC - 1) rc = SEGC - 1;   // tile3 = 0
        trS[l] = (seg0 + rc) * DIMP + trG2[l] * 8;
    }

#define STAGE(BUF, KK3) do {                                                    \
    const int ke_ = (KK3) * BK2;                                                \
    global_load_lds16(test_bf  + tS[0]  + ke_, &AB[(BUF)][(0 * 256 + tid) * 8]);\
    global_load_lds16(test_bf  + tS[1]  + ke_, &AB[(BUF)][(1 * 256 + tid) * 8]);\
    global_load_lds16(train_bf + trS[0] + ke_, &AB[(BUF)][(2 * 256 + tid) * 8]);\
    global_load_lds16(train_bf + trS[1] + ke_, &AB[(BUF)][(3 * 256 + tid) * 8]);\
} while (0)

    // prologue: stage steps 0,1,2 (tile 0, kk 0..2) -> bufs 0,1,2 (12 loads in flight)
    STAGE(0, 0);
    STAGE(1, 1);
    STAGE(2, 2);

    int cur = 0;
    int kk = 0, n_base = 0;
    int kk3 = 3, tile3 = 0, n3 = 0;

    for (int g = 0; g < NSTEPS; ++g) {
        asm volatile("s_waitcnt vmcnt(8)" ::: "memory");   // own oldest 4 (step g) landed
        MEMFENCE();
        __builtin_amdgcn_s_barrier();                      // => ALL waves' step-g loads landed
        __builtin_amdgcn_sched_barrier(0);
        MEMFENCE();                                        // LDS reads may not hoist above barrier

        // compute step g from AB[cur]
        {
            bf16x8 aF[4];
            #pragma unroll
            for (int i = 0; i < 4; ++i)
                aF[i] = *(const bf16x8*)&AB[cur][aOffE[i]];
            #pragma unroll
            for (int j = 0; j < 4; ++j) {
                const bf16x8 bF = *(const bf16x8*)&AB[cur][bOffE[j]];
                #pragma unroll
                for (int i = 0; i < 4; ++i)
                    acc[i][j] = __builtin_amdgcn_mfma_f32_16x16x32_bf16(
                        aF[i], bF, acc[i][j], 0, 0, 0);
            }
        }

        MEMFENCE();                                        // LDS reads may not sink below barrier
        __builtin_amdgcn_s_barrier();                      // all waves done reading AB[cur]
        __builtin_amdgcn_sched_barrier(0);
        MEMFENCE();                                        // STAGE may not hoist above barrier (!)

        STAGE(cur, kk3);                                   // issue step g+3 into freed buffer

        // ---- tile end: float-gated in-register selection (registers only) ----
        if (kk == KSTEPS - 1) {
            #pragma unroll
            for (int j = 0; j < 4; ++j) {
                #pragma unroll
                for (int i = 0; i < 4; ++i) {
                    #pragma unroll
                    for (int r = 0; r < 4; ++r) {
                        const int lidx = n_base + wc * 64 + i * 16 + l4 * 4 + r;
                        const float f = -acc[i][j][r];     // rank of f == rank of score
                        if (lidx < SEGC && !(f >= tailF[j])) {
                            const unsigned u    = __float_as_uint(f);
                            const unsigned mono = u ^ ((unsigned)((int)u >> 31) | 0x80000000u);
                            const unsigned key  = (mono & 0xFFFFE000u) | (unsigned)lidx;
                            kinsert(key, lst[j]);
                            const unsigned tk = lst[j][LSEL - 1] | 0x1FFFu;
                            const unsigned tu = (tk & 0x80000000u) ? (tk ^ 0x80000000u) : ~tk;
                            tailF[j] = __uint_as_float(tu);
                        }
                        acc[i][j][r] = 0.f;
                    }
                }
            }
            kk = 0; n_base += BNT;
        } else {
            ++kk;
        }

        // advance staging coords
        if (++kk3 == KSTEPS) {
            kk3 = 0;
            if (tile3 < NTILES - 1) { ++tile3; n3 += BNT; }
            #pragma unroll
            for (int l = 0; l < 2; ++l) {
                int rc = n3 + trR[l]; if (rc > SEGC - 1) rc = SEGC - 1;
                trS[l] = (seg0 + rc) * DIMP + trG2[l] * 8;
            }
        }
        cur = (cur == 2) ? 0 : cur + 1;
    }

    // drain ALL in-flight staging before overlaying merge buffer on AB
    asm volatile("s_waitcnt vmcnt(0)" ::: "memory");
    MEMFENCE();
    __builtin_amdgcn_s_barrier();
    __builtin_amdgcn_sched_barrier(0);
    MEMFENCE();

    // -------- end-of-WG merge (overlay on AB): per row, 8 buckets x 8 -> top-24 --------
    unsigned* MgU = (unsigned*)&AB[0][0];          // [32 rows][8 buckets][LSEL]
    #pragma unroll
    for (int c = 0; c < 4; ++c) {                  // chunk c = rows [c*32, c*32+32)
        __syncthreads();
        if (wr == (c >> 1)) {
            #pragma unroll
            for (int jj = 0; jj < 2; ++jj) {
                const int j = (c & 1) * 2 + jj;
                #pragma unroll
                for (int s = 0; s < LSEL; ++s)
                    MgU[((jj * 16 + l15) * 8 + (wc * 4 + l4)) * 8 + s] = lst[j][s];
            }
        }
        __syncthreads();
        const int mrow = tid >> 3, mb = tid & 7;
        unsigned mine[LSEL];
        #pragma unroll
        for (int s = 0; s < LSEL; ++s) mine[s] = MgU[(mrow * 8 + mb) * 8 + s];
        int rank[LSEL];
        #pragma unroll
        for (int s = 0; s < LSEL; ++s) rank[s] = 0;
        #pragma unroll
        for (int ob = 0; ob < 8; ++ob) {
            #pragma unroll
            for (int os = 0; os < LSEL; ++os) {
                const unsigned ok = MgU[(mrow * 8 + ob) * 8 + os];
                #pragma unroll
                for (int s = 0; s < LSEL; ++s) rank[s] += (ok < mine[s]) ? 1 : 0;
            }
        }
        const int grow = m_base + c * 32 + mrow;
        if (grow < NTEST) {
            #pragma unroll
            for (int s = 0; s < LSEL; ++s)
                if (rank[s] < DUMP)
                    cand[((size_t)grow * NSEG + seg) * DUMP + rank[s]] = mine[s];
        }
    }
#undef STAGE
}

// ======================= K2: cut 192 -> 48 by approx key (round-5 verified) =======================
__global__ void cut48k(const unsigned* __restrict__ cand, int* __restrict__ cut)
{
    __shared__ unsigned long long C[8][CPR];           // 8 x 192 x 8B = 12 KB
    const int tid = threadIdx.x;
    const int rw = tid >> 5;
    const int l32 = tid & 31;
    const int row = blockIdx.x * 8 + rw;               // grid*8 == NTEST exactly
    #pragma unroll
    for (int t = 0; t < 6; ++t) {
        const int e = l32 + t * 32;
        const unsigned key = cand[(size_t)row * CPR + e];
        const int sg = e / DUMP;
        const unsigned gidx = (unsigned)(sg * SEGC) + (key & 0x1FFFu);
        C[rw][e] = ((unsigned long long)(key >> 13) << 32) | gidx;
    }
    __syncthreads();
    #pragma unroll
    for (int t = 0; t < 6; ++t) {
        const int e = l32 + t * 32;
        const unsigned long long mk = C[rw][e];
        int rank = 0;
        for (int o = 0; o < CPR; ++o) rank += (C[rw][o] < mk) ? 1 : 0;
        if (rank < KCAND) cut[(size_t)row * KCAND + rank] = (int)(mk & 0xFFFFFFFFULL);
    }
}

// ======================= K3: exact np-f32 d2 for 48 candidates =======================
__global__ void npd2_kernel(const float* __restrict__ train_x,
                            const float* __restrict__ test_x,
                            const float* __restrict__ np_trs,
                            const float* __restrict__ np_tests,
                            const int* __restrict__ cut,
                            float* __restrict__ d2)
{
#pragma clang fp contract(off)
    const int T = blockIdx.x * 256 + threadIdx.x;
    if (T >= NTEST * KCAND) return;
    const int row = T / KCAND;
    const int idx = cut[T];
    const float dt = np_dot512(test_x + (size_t)row * DIM, train_x + (size_t)idx * DIM);
    const float Tv = np_tests[row] + np_trs[idx];   // f32 round
    const float w  = 2.0f * dt;                     // exact
    d2[T] = Tv - w;                                 // f32 round, no contraction
}

// ======================= K4: top-32 select + label mean =======================
__global__ void select_out(const float* __restrict__ train_y,
                           const int* __restrict__ cut,
                           const float* __restrict__ d2,
                           float* __restrict__ out)
{
    __shared__ float D[4][KCAND];
    __shared__ int   I[4][KCAND];
    __shared__ int   S[4][KNN];
    const int wid = threadIdx.x >> 6, lane = threadIdx.x & 63;
    const int row = blockIdx.x * 4 + wid;        // grid*4 == NTEST exactly
    if (lane < KCAND) {
        D[wid][lane] = d2[(size_t)row * KCAND + lane];
        I[wid][lane] = cut[(size_t)row * KCAND + lane];
    }
    __syncthreads();
    if (lane < KCAND) {
        const float ms = D[wid][lane]; const int mi = I[wid][lane];
        int rank = 0;
        #pragma unroll
        for (int o = 0; o < KCAND; ++o)
            rank += (D[wid][o] < ms || (D[wid][o] == ms && I[wid][o] < mi)) ? 1 : 0;
        if (rank < KNN) S[wid][rank] = mi;       // (dist, idx) order == lax.top_k
    }
    __syncthreads();
    float s = 0.f;
    #pragma unroll
    for (int n = 0; n < KNN; ++n)
        s += train_y[(size_t)S[wid][n] * NCOMP + lane];
    out[(size_t)row * NCOMP + lane] = s * (1.0f / KNN);
}

// ======================= fallback: round-3 monolithic kernel =======================
#define FM_TILE 32
#define FN_TILE 256
#define FK_CHUNK 16
__global__ __launch_bounds__(256, 2)
void knn_fallback(const float* __restrict__ train_x,
                  const float* __restrict__ train_y,
                  const float* __restrict__ test_x,
                  float* __restrict__ out)
{
    __shared__ float As[FK_CHUNK][FM_TILE];
    __shared__ float Bs[FK_CHUNK][FN_TILE];
    __shared__ float Scb[FM_TILE][FN_TILE + 1];
    __shared__ float colSq[FN_TILE];
    __shared__ float topD[FM_TILE][64];
    __shared__ int   topI[FM_TILE][64];

    const int tid    = threadIdx.x;
    const int m_base = blockIdx.x * FM_TILE;
    const int tx     = tid & 31;
    const int ty     = tid >> 5;

    for (int i = tid; i < FM_TILE * 64; i += 256) {
        (&topD[0][0])[i] = FLT_MAX;
        (&topI[0][0])[i] = 0;
    }
    float rowMax = FLT_MAX;
    const int a_row  = tid >> 2;
    const int a_k    = (tid & 3) * 4;
    const int a_grow = (m_base + a_row < NTEST) ? (m_base + a_row) : (NTEST - 1);

    for (int n_base = 0; n_base < NTRAIN; n_base += FN_TILE) {
        float accf[4][8];
        #pragma unroll
        for (int i = 0; i < 4; ++i)
            #pragma unroll
            for (int j = 0; j < 8; ++j) accf[i][j] = 0.f;
        int b_row = n_base + tid;
        if (b_row >= NTRAIN) b_row = NTRAIN - 1;
        const float* bp = train_x + (size_t)b_row * DIM;
        float sq_acc = 0.f;
        for (int k_base = 0; k_base < DIM; k_base += FK_CHUNK) {
            __syncthreads();
            if (tid < 128) {
                const float4 v = *(const float4*)(test_x + (size_t)a_grow * DIM + k_base + a_k);
                As[a_k + 0][a_row] = v.x; As[a_k + 1][a_row] = v.y;
                As[a_k + 2][a_row] = v.z; As[a_k + 3][a_row] = v.w;
            }
            {
                const float4* tp = (const float4*)(bp + k_base);
                const float4 v0 = tp[0], v1 = tp[1], v2 = tp[2], v3 = tp[3];
                Bs[0][tid]=v0.x; Bs[1][tid]=v0.y; Bs[2][tid]=v0.z; Bs[3][tid]=v0.w;
                Bs[4][tid]=v1.x; Bs[5][tid]=v1.y; Bs[6][tid]=v1.z; Bs[7][tid]=v1.w;
                Bs[8][tid]=v2.x; Bs[9][tid]=v2.y; Bs[10][tid]=v2.z; Bs[11][tid]=v2.w;
                Bs[12][tid]=v3.x; Bs[13][tid]=v3.y; Bs[14][tid]=v3.z; Bs[15][tid]=v3.w;
                sq_acc += v0.x*v0.x+v0.y*v0.y+v0.z*v0.z+v0.w*v0.w
                        + v1.x*v1.x+v1.y*v1.y+v1.z*v1.z+v1.w*v1.w
                        + v2.x*v2.x+v2.y*v2.y+v2.z*v2.z+v2.w*v2.w
                        + v3.x*v3.x+v3.y*v3.y+v3.z*v3.z+v3.w*v3.w;
            }
            __syncthreads();
            #pragma unroll
            for (int k = 0; k < FK_CHUNK; ++k) {
                const float4 av  = *(const float4*)&As[k][ty * 4];
                const float4 bv0 = *(const float4*)&Bs[k][tx * 8];
                const float4 bv1 = *(const float4*)&Bs[k][tx * 8 + 4];
                const float a[4] = {av.x, av.y, av.z, av.w};
                const float b[8] = {bv0.x, bv0.y, bv0.z, bv0.w, bv1.x, bv1.y, bv1.z, bv1.w};
                #pragma unroll
                for (int i = 0; i < 4; ++i)
                    #pragma unroll
                    for (int j = 0; j < 8; ++j)
                        accf[i][j] = fmaf(a[i], b[j], accf[i][j]);
            }
        }
        colSq[tid] = sq_acc;
        __syncthreads();
        #pragma unroll
        for (int i = 0; i < 4; ++i)
            #pragma unroll
            for (int j = 0; j < 8; ++j) {
                const int c = tx * 8 + j;
                const int gcol = n_base + c;
                Scb[ty * 4 + i][c] = (gcol < NTRAIN) ? (colSq[c] - 2.f * accf[i][j]) : FLT_MAX;
            }
        __syncthreads();
        if (tid < FM_TILE) {
            float rmax = rowMax;
            for (int c = 0; c < FN_TILE; ++c) {
                const float s = Scb[tid][c];
                if (s < rmax) {
                    int bi = 0; float bv = topD[tid][0]; int bidx = topI[tid][0];
                    #pragma unroll
                    for (int i = 1; i < 64; ++i) {
                        const float v = topD[tid][i]; const int idv = topI[tid][i];
                        if (v > bv || (v == bv && idv > bidx)) { bv = v; bi = i; bidx = idv; }
                    }
                    topD[tid][bi] = s; topI[tid][bi] = n_base + c;
                    float nm = -FLT_MAX;
                    #pragma unroll
                    for (int i = 0; i < 64; ++i) nm = fmaxf(nm, topD[tid][i]);
                    rmax = nm;
                }
            }
            rowMax = rmax;
        }
        __syncthreads();
    }
    float* Sf = &Scb[0][0];
    {
#pragma clang fp contract(off)
        const int r = tid >> 3, j0 = tid & 7;
        int grow = m_base + r; if (grow >= NTEST) grow = NTEST - 1;
        const float* tp = test_x + (size_t)grow * DIM;
        const float ts = np_sq512(tp);
        for (int jj = j0; jj < 64; jj += 8) {
            const int idx = topI[r][jj];
            const float* xp = train_x + (size_t)idx * DIM;
            const float trsv = np_sq512(xp);
            const float dt = np_dot512(tp, xp);
            const float T = ts + trsv;
            const float w = 2.0f * dt;
            Sf[r * 64 + jj] = T - w;
        }
    }
    __syncthreads();
    int* sel = (int*)&topD[0][0];
    if (tid < FM_TILE) {
        const int r = tid;
        unsigned long long used = 0ULL;
        for (int p = 0; p < KNN; ++p) {
            float bv = FLT_MAX; int bj = 0; int bidx = 0x7fffffff;
            for (int j = 0; j < 64; ++j) {
                if (used & (1ULL << j)) continue;
                const float v = Sf[r * 64 + j];
                const int idv = topI[r][j];
                if (v < bv || (v == bv && idv < bidx)) { bv = v; bj = j; bidx = idv; }
            }
            used |= (1ULL << bj);
            sel[r * KNN + p] = bidx;
        }
    }
    __syncthreads();
    const int r = tid >> 3, c0 = (tid & 7) * 8;
    const int grow = m_base + r;
    if (grow < NTEST) {
        float s0=0,s1=0,s2=0,s3=0,s4=0,s5=0,s6=0,s7=0;
        for (int n = 0; n < KNN; ++n) {
            const float* yp = train_y + (size_t)sel[r * KNN + n] * NCOMP + c0;
            const float4 y0 = *(const float4*)yp;
            const float4 y1 = *(const float4*)(yp + 4);
            s0+=y0.x; s1+=y0.y; s2+=y0.z; s3+=y0.w;
            s4+=y1.x; s5+=y1.y; s6+=y1.z; s7+=y1.w;
        }
        const float inv = 1.0f / KNN;
        float* op = out + (size_t)grow * NCOMP + c0;
        *(float4*)op       = make_float4(s0*inv, s1*inv, s2*inv, s3*inv);
        *(float4*)(op + 4) = make_float4(s4*inv, s5*inv, s6*inv, s7*inv);
    }
}

// ======================= launcher =======================
extern "C" void kernel_launch(void* const* d_in, const int* in_sizes, int n_in,
                              void* d_out, int out_size, void* d_ws, size_t ws_size,
                              hipStream_t stream) {
    const float* train_x = (const float*)d_in[0];
    const float* train_y = (const float*)d_in[1];
    const float* test_x  = (const float*)d_in[2];
    float* out = (float*)d_out;

    if (ws_size < WS_NEED) {
        knn_fallback<<<(NTEST + FM_TILE - 1) / FM_TILE, 256, 0, stream>>>(
            train_x, train_y, test_x, out);
        return;
    }

    char* ws = (char*)d_ws;
    unsigned short* train_bf = (unsigned short*)(ws + OFF_TRAINBF);
    unsigned short* test_bf  = (unsigned short*)(ws + OFF_TESTBF);
    float*  np_trs   = (float*)(ws + OFF_NPTRS);
    float*  np_tests = (float*)(ws + OFF_NPTESTS);
    unsigned* cand   = (unsigned*)(ws + OFF_CAND);
    int*    cut      = (int*)(ws + OFF_CUT);
    float*  d2       = (float*)(ws + OFF_D2);

    prep_convert<<<(NTRAIN + NTEST) / 4, 256, 0, stream>>>(train_x, test_x, train_bf, test_bf);
    prep_npnorm<<<(NTRAIN + NTEST + 255) / 256, 256, 0, stream>>>(train_x, test_x, np_trs, np_tests);
    stageA<<<MTILES * NSEG, 256, 0, stream>>>(train_bf, test_bf, cand);
    cut48k<<<NTEST / 8, 256, 0, stream>>>(cand, cut);
    npd2_kernel<<<(NTEST * KCAND + 255) / 256, 256, 0, stream>>>(train_x, test_x, np_trs, np_tests, cut, d2);
    select_out<<<NTEST / 4, 256, 0, stream>>>(train_y, cut, d2, out);
}